// Round 11
// baseline (326.824 us; speedup 1.0000x reference)
//
#include <hip/hip_runtime.h>
#include <hip/hip_bf16.h>

#define DEVI __device__ __forceinline__

typedef _Float16 h2f16 __attribute__((ext_vector_type(2)));
typedef _Float16 f16x4 __attribute__((ext_vector_type(4)));
typedef _Float16 f16x8 __attribute__((ext_vector_type(8)));
typedef float    f32x4 __attribute__((ext_vector_type(4)));
union U4H { uint4 u; h2f16 h[4]; };
union F8  { f16x8 v8; f16x4 v4[2]; };

DEVI float sigf(float x){ return 1.f/(1.f + __expf(-x)); }
DEVI float tanh_f(float x){
  float ax = fabsf(x);
  float e = __expf(-2.f*ax);
  float t = (1.f - e)/(1.f + e);
  return copysignf(t, x);
}
DEVI h2f16 hmax2(h2f16 a, h2f16 b){
  h2f16 r; r[0] = a[0] > b[0] ? a[0] : b[0]; r[1] = a[1] > b[1] ? a[1] : b[1]; return r;
}

// ---------------------------------------------------------------------------
// K0: fused prep. bid 0: adjacency; 1..24: conv w pack; 25..5240: GEMM w pack;
// 5241..7288: w_hh transpose+pack (4 matrices).
// ---------------------------------------------------------------------------
__global__ __launch_bounds__(256) void k_prep(
  const int* __restrict__ ei, float* __restrict__ An,
  const float* __restrict__ w2, const float* __restrict__ w3,
  const float* __restrict__ bg2, const float* __restrict__ bg3,
  _Float16* __restrict__ bw2f, _Float16* __restrict__ bw3f,
  const float* __restrict__ a0, const float* __restrict__ a1,
  const float* __restrict__ a2, const float* __restrict__ a3,
  const float* __restrict__ a4, const float* __restrict__ a5,
  _Float16* __restrict__ o0, _Float16* __restrict__ o1,
  _Float16* __restrict__ o2, _Float16* __restrict__ o3,
  _Float16* __restrict__ o4, _Float16* __restrict__ o5,
  const float* __restrict__ whh0, const float* __restrict__ whh0r,
  const float* __restrict__ whh1, const float* __restrict__ whh1r,
  h2f16* __restrict__ wt0f, h2f16* __restrict__ wt0r,
  h2f16* __restrict__ wt1f, h2f16* __restrict__ wt1r)
{
  const int bid = blockIdx.x, tid = threadIdx.x;
  if (bid == 0){
    __shared__ float A[64];
    __shared__ float dinv[8];
    if (tid<64) A[tid] = ((tid>>3)==(tid&7)) ? 1.f : 0.f;
    __syncthreads();
    if (tid==0){
      for (int e=0;e<56;e++){ int s=ei[e], d=ei[56+e]; A[d*8+s] += 1.f; }
    }
    __syncthreads();
    if (tid<8){ float s=0.f; for (int j=0;j<8;j++) s+=A[tid*8+j]; dinv[tid]=rsqrtf(s); }
    __syncthreads();
    if (tid<64) An[tid] = A[tid]*dinv[tid>>3]*dinv[tid&7];
    return;
  }
  if (bid <= 24){
    const int i = (bid-1)*256 + tid;
    const float rs = rsqrtf(1.f+1e-5f);
    if (i < 3072){
      const int j = i&7, m = (i>>3)&15, g = (i>>7)&3, nt = (i>>9)&1, s = i>>10;
      const int kk = 32*s + 8*g + j;
      const int k = kk >> 4, ic = kk & 15, oc = nt*16 + m;
      bw2f[i] = (_Float16)((k < 5 ? w2[oc*80 + ic*5 + k] : 0.f) * (bg2[oc]*rs));
    }
    if (i < 6144){
      const int j = i&7, m = (i>>3)&15, g = (i>>7)&3, wv = (i>>9)&3, s = i>>11;
      const int kk = 32*s + 8*g + j;
      const int k = kk >> 5, ic = kk & 31, oc = wv*16 + m;
      bw3f[i] = (_Float16)(w3[oc*96 + ic*3 + k] * (bg3[oc]*rs));
    }
    return;
  }
  if (bid <= 5240){
    const int i = (bid-25)*256 + tid;
    if      (i <  131072) o0[i] = (_Float16)a0[i];
    else if (i <  262144) o1[i-131072] = (_Float16)a1[i-131072];
    else if (i <  786432) o2[i-262144] = (_Float16)a2[i-262144];
    else if (i < 1310720) o3[i-786432] = (_Float16)a3[i-786432];
    else if (i < 1318912) o4[i-1310720] = (_Float16)a4[i-1310720];
    else if (i < 1335296) o5[i-1318912] = (_Float16)a5[i-1318912];
    return;
  }
  {
    const int idx = (bid-5241)*256 + tid;        // [0, 524288)
    const int which = idx >> 17, i = idx & 131071;
    const int g = i & 1023, jp = i >> 10;
    const float* in = (which==0) ? whh0 : (which==1) ? whh0r : (which==2) ? whh1 : whh1r;
    h2f16* outp    = (which==0) ? wt0f : (which==1) ? wt0r  : (which==2) ? wt1f : wt1r;
    h2f16 p;
    p[0] = (_Float16)in[g*256 + 2*jp];
    p[1] = (_Float16)in[g*256 + 2*jp + 1];
    outp[(long)jp*1024 + g] = p;
  }
}

// ---------------------------------------------------------------------------
// K1: fused conv front-end, 512 threads (8 waves) -> 4 blocks/CU = 32 waves/CU.
// Phase A: conv1 fdot2. Phase B (conv2), C (conv3): MFMA 16x16x32 f16.
// LDS ~39.9 KB.
// ---------------------------------------------------------------------------
__global__ __launch_bounds__(512,8) void k_conv(
    const float* __restrict__ x,
    const float* __restrict__ w1g, const float* __restrict__ c1b,
    const float* __restrict__ bg1, const float* __restrict__ bb1,
    const _Float16* __restrict__ bw2f,
    const float* __restrict__ c2b, const float* __restrict__ bg2, const float* __restrict__ bb2,
    const _Float16* __restrict__ bw3f,
    const float* __restrict__ c3b, const float* __restrict__ bg3, const float* __restrict__ bb3,
    _Float16* __restrict__ feats)
{
  __shared__ __align__(16) unsigned char smb[38592];
  __shared__ h2f16 w1p[16][4];
  __shared__ float kb1o[16], kb2o[32], kb3o[64];
  __shared__ float redc[8][16];
  h2f16* sxh = reinterpret_cast<h2f16*>(smb + 20160);
  const int tid = threadIdx.x;
  const long sig = blockIdx.x;
  const float* xg = x + sig*3000;

  {
    const float4* xg4 = reinterpret_cast<const float4*>(xg);
    for (int i=tid; i<750; i+=512){
      float4 v = xg4[i];
      h2f16 p0; p0[0]=(_Float16)v.x; p0[1]=(_Float16)v.y;
      h2f16 p1; p1[0]=(_Float16)v.z; p1[1]=(_Float16)v.w;
      sxh[2*i+2] = p0; sxh[2*i+3] = p1;
    }
    if (tid<3){
      h2f16 z; z[0]=(_Float16)0.f; z[1]=(_Float16)0.f;
      sxh[tid<2 ? tid : 1502] = z;
    }
    if (tid<32){
      const int rr = tid>>3, cp = tid&7;
      const int row = (rr<2) ? rr : (500+rr);
      h2f16 z; z[0]=(_Float16)0.f; z[1]=(_Float16)0.f;
      *reinterpret_cast<h2f16*>(smb + row*40 + 4*cp) = z;
    }
    const float rs = rsqrtf(1.f+1e-5f);
    if (tid<64){
      const int c = tid>>2, j = tid&3;
      const float s = bg1[c]*rs;
      h2f16 p;
      if (j==0){ p[0]=(_Float16)0.f; p[1]=(_Float16)(w1g[c*7+0]*s); }
      else     { p[0]=(_Float16)(w1g[c*7+2*j-1]*s); p[1]=(_Float16)(w1g[c*7+2*j]*s); }
      w1p[c][j] = p;
    }
    if (tid<16) kb1o[tid] = c1b[tid]*(bg1[tid]*rs) + bb1[tid];
    if (tid<32) kb2o[tid] = c2b[tid]*(bg2[tid]*rs) + bb2[tid];
    if (tid<64) kb3o[tid] = c3b[tid]*(bg3[tid]*rs) + bb3[tid];
  }
  __syncthreads();

  // Phase A: conv1+bn+relu+pool -> s1t rows (u+2), 2 channels per thread
  {
    const int cp = tid & 7;
    h2f16 wpa[4], wpb[4];
    #pragma unroll
    for (int j=0;j<4;j++){ wpa[j] = w1p[2*cp][j]; wpb[j] = w1p[2*cp+1][j]; }
    const float oa = kb1o[2*cp], ob = kb1o[2*cp+1];
    for (int u = tid>>3; u<500; u+=64){
      h2f16 xq[6];
      #pragma unroll
      for (int r=0;r<6;r++) xq[r] = sxh[3*u + r];
      float a0=0.f,a1=0.f,a2=0.f,b0=0.f,b1=0.f,b2=0.f;
      #pragma unroll
      for (int j=0;j<4;j++){
        a0 = __builtin_amdgcn_fdot2(xq[j],   wpa[j], a0, false);
        a1 = __builtin_amdgcn_fdot2(xq[j+1], wpa[j], a1, false);
        a2 = __builtin_amdgcn_fdot2(xq[j+2], wpa[j], a2, false);
        b0 = __builtin_amdgcn_fdot2(xq[j],   wpb[j], b0, false);
        b1 = __builtin_amdgcn_fdot2(xq[j+1], wpb[j], b1, false);
        b2 = __builtin_amdgcn_fdot2(xq[j+2], wpb[j], b2, false);
      }
      const float ya = fmaxf(fmaxf(fmaxf(a0,a1),a2) + oa, 0.f);
      const float yb = fmaxf(fmaxf(fmaxf(b0,b1),b2) + ob, 0.f);
      h2f16 p; p[0]=(_Float16)ya; p[1]=(_Float16)yb;
      *reinterpret_cast<h2f16*>(smb + (u+2)*40 + 4*cp) = p;
    }
  }
  __syncthreads();

  const int wv = tid >> 6, lane = tid & 63;
  const int m = lane & 15, g = lane >> 4;

  // Phase B: conv2 as MFMA. M=256 (t), K=96, N=32. 8 waves: nt=wv&1,
  // mt=(wv>>1)+4i.
  {
    const int nt = wv & 1;
    f16x8 bf[3];
    #pragma unroll
    for (int s=0;s<3;s++)
      bf[s] = *reinterpret_cast<const f16x8*>(&bw2f[(((s*2+nt)*4+g)*16+m)*8]);
    const int oc = nt*16 + m;
    const float of = kb2o[oc];
    #pragma unroll
    for (int i=0;i<4;i++){
      const int mt = (wv>>1) + 4*i;
      const int trow = mt*16 + m;
      f32x4 acc = {0.f,0.f,0.f,0.f};
      #pragma unroll
      for (int s=0;s<3;s++){
        const int kk = 32*s + 8*g;
        const int k = kk >> 4;
        const int ab = 80*trow + 40*k + 16*(g&1);
        F8 a;
        a.v4[0] = *reinterpret_cast<const f16x4*>(smb + ab);
        a.v4[1] = *reinterpret_cast<const f16x4*>(smb + ab + 8);
        acc = __builtin_amdgcn_mfma_f32_16x16x32_f16(a.v8, bf[s], acc, 0,0,0);
      }
      #pragma unroll
      for (int r=0;r<4;r++){
        const int t = mt*16 + 4*g + r;
        const float z = fmaxf(acc[r] + of, 0.f);
        *reinterpret_cast<_Float16*>(smb + 20160 + t*72 + 2*oc) = (_Float16)z;
      }
    }
  }
  __syncthreads();

  // Pool
  {
    if (tid < 240){
      const int rr = tid >> 4, cc = tid & 15;
      const int row = (rr == 0) ? 0 : (83 + rr);
      h2f16 z; z[0]=(_Float16)0.f; z[1]=(_Float16)0.f;
      *reinterpret_cast<h2f16*>(smb + row*80 + 4*cc) = z;
    }
    for (int i=tid; i<1328; i+=512){
      const int u = i >> 4, cc = i & 15;
      h2f16 a = *reinterpret_cast<const h2f16*>(smb + 20160 + (3*u)*72 + 4*cc);
      h2f16 b = *reinterpret_cast<const h2f16*>(smb + 20160 + (3*u+1)*72 + 4*cc);
      h2f16 c = *reinterpret_cast<const h2f16*>(smb + 20160 + (3*u+2)*72 + 4*cc);
      *reinterpret_cast<h2f16*>(smb + (u+1)*80 + 4*cc) = hmax2(hmax2(a,b), c);
    }
  }
  __syncthreads();

  // Phase C: conv3 as MFMA + bn+relu+mean. 8 waves: nt=wv&3, mt=(wv>>2)+2q;
  // cross-wave reduce via redc.
  {
    const int nt = wv & 3;
    f16x8 bf[3];
    #pragma unroll
    for (int s=0;s<3;s++)
      bf[s] = *reinterpret_cast<const f16x8*>(&bw3f[(((s*4+nt)*4+g)*16+m)*8]);
    const int oc = nt*16 + m;
    const float of = kb3o[oc];
    float macc = 0.f;
    #pragma unroll
    for (int q=0;q<3;q++){
      const int mt = (wv>>2) + 2*q;
      const int trow = mt*16 + m;
      f32x4 acc = {0.f,0.f,0.f,0.f};
      #pragma unroll
      for (int s=0;s<3;s++){
        f16x8 af = *reinterpret_cast<const f16x8*>(smb + (trow + s)*80 + 16*g);
        acc = __builtin_amdgcn_mfma_f32_16x16x32_f16(af, bf[s], acc, 0,0,0);
      }
      #pragma unroll
      for (int r=0;r<4;r++){
        const int t = mt*16 + 4*g + r;
        if (t < 83) macc += fmaxf(acc[r] + of, 0.f);
      }
    }
    macc += __shfl_xor(macc, 16);
    macc += __shfl_xor(macc, 32);
    if (lane < 16) redc[wv][m] = macc;
  }
  __syncthreads();
  if (tid < 64)
    feats[sig*64 + tid] = (_Float16)((redc[tid>>4][tid&15] + redc[(tid>>4)+4][tid&15]) * (1.f/83.f));
}

// ---------------------------------------------------------------------------
// K3: MFMA f16 GEMM (single-W): C = X16 @ W16^T (+b1+b2), f32 out.
// ---------------------------------------------------------------------------
__global__ __launch_bounds__(256) void k_gemm_mf(
  const _Float16* __restrict__ X, const _Float16* __restrict__ W,
  const float* __restrict__ b1, const float* __restrict__ b2,
  float* __restrict__ C, int M, int N, int K, int ldc)
{
  __shared__ __align__(16) unsigned char lds[128*72];
  unsigned char* Xs = lds;
  unsigned char* Ws = lds + 64*72;
  const int tid = threadIdx.x;
  const int m0 = blockIdx.y*64, n0 = blockIdx.x*64;
  const int wv = tid>>6, lane = tid&63, m = lane&15, g = lane>>4;
  const int sr = tid>>2, sq = tid&3;
  f32x4 acc[4] = {{0.f,0.f,0.f,0.f},{0.f,0.f,0.f,0.f},{0.f,0.f,0.f,0.f},{0.f,0.f,0.f,0.f}};
  for (int k0=0; k0<K; k0+=32){
    uint4 xa = *reinterpret_cast<const uint4*>(X + (long)(m0+sr)*K + k0 + sq*8);
    uint4 wa = *reinterpret_cast<const uint4*>(W + (long)(n0+sr)*K + k0 + sq*8);
    __syncthreads();
    *reinterpret_cast<uint4*>(Xs + sr*72 + sq*16) = xa;
    *reinterpret_cast<uint4*>(Ws + sr*72 + sq*16) = wa;
    __syncthreads();
    f16x8 af = *reinterpret_cast<const f16x8*>(Xs + (wv*16+m)*72 + g*16);
    #pragma unroll
    for (int nt=0;nt<4;nt++){
      f16x8 bf = *reinterpret_cast<const f16x8*>(Ws + (nt*16+m)*72 + g*16);
      acc[nt] = __builtin_amdgcn_mfma_f32_16x16x32_f16(af, bf, acc[nt], 0,0,0);
    }
  }
  #pragma unroll
  for (int nt=0;nt<4;nt++){
    const int col = n0 + nt*16 + m;
    float bias = 0.f;
    if (b1) bias += b1[col];
    if (b2) bias += b2[col];
    #pragma unroll
    for (int r=0;r<4;r++)
      C[(long)(m0 + wv*16 + g*4 + r)*ldc + col] = acc[nt][r] + bias;
  }
}

// ---------------------------------------------------------------------------
// K3b: dual-W MFMA GEMM: blockIdx.z selects (Wa,b1a,b2a,C) vs (Wb,b1b,b2b,C+co)
// ---------------------------------------------------------------------------
__global__ __launch_bounds__(256) void k_gemm_mf2(
  const _Float16* __restrict__ X,
  const _Float16* __restrict__ Wa, const _Float16* __restrict__ Wb,
  const float* __restrict__ b1a, const float* __restrict__ b2a,
  const float* __restrict__ b1b, const float* __restrict__ b2b,
  float* __restrict__ C, int co, int M, int N, int K, int ldc)
{
  __shared__ __align__(16) unsigned char lds[128*72];
  unsigned char* Xs = lds;
  unsigned char* Ws = lds + 64*72;
  const int z = blockIdx.z;
  const _Float16* W = z ? Wb : Wa;
  const float* b1 = z ? b1b : b1a;
  const float* b2 = z ? b2b : b2a;
  float* Cz = C + (z ? co : 0);
  const int tid = threadIdx.x;
  const int m0 = blockIdx.y*64, n0 = blockIdx.x*64;
  const int wv = tid>>6, lane = tid&63, m = lane&15, g = lane>>4;
  const int sr = tid>>2, sq = tid&3;
  f32x4 acc[4] = {{0.f,0.f,0.f,0.f},{0.f,0.f,0.f,0.f},{0.f,0.f,0.f,0.f},{0.f,0.f,0.f,0.f}};
  for (int k0=0; k0<K; k0+=32){
    uint4 xa = *reinterpret_cast<const uint4*>(X + (long)(m0+sr)*K + k0 + sq*8);
    uint4 wa = *reinterpret_cast<const uint4*>(W + (long)(n0+sr)*K + k0 + sq*8);
    __syncthreads();
    *reinterpret_cast<uint4*>(Xs + sr*72 + sq*16) = xa;
    *reinterpret_cast<uint4*>(Ws + sr*72 + sq*16) = wa;
    __syncthreads();
    f16x8 af = *reinterpret_cast<const f16x8*>(Xs + (wv*16+m)*72 + g*16);
    #pragma unroll
    for (int nt=0;nt<4;nt++){
      f16x8 bf = *reinterpret_cast<const f16x8*>(Ws + (nt*16+m)*72 + g*16);
      acc[nt] = __builtin_amdgcn_mfma_f32_16x16x32_f16(af, bf, acc[nt], 0,0,0);
    }
  }
  #pragma unroll
  for (int nt=0;nt<4;nt++){
    const int col = n0 + nt*16 + m;
    float bias = b1[col] + b2[col];
    #pragma unroll
    for (int r=0;r<4;r++)
      Cz[(long)(m0 + wv*16 + g*4 + r)*ldc + col] = acc[nt][r] + bias;
  }
}

// ---------------------------------------------------------------------------
// K4: g1 mix (f16 out)
// ---------------------------------------------------------------------------
__global__ __launch_bounds__(256) void k_mix1(
  const float* __restrict__ tmp0, const float* __restrict__ An,
  const float* __restrict__ b0, _Float16* __restrict__ g1)
{
  __shared__ float ans[64];
  if (threadIdx.x < 64) ans[threadIdx.x] = An[threadIdx.x];
  __syncthreads();
  const long idx = (long)blockIdx.x*256 + threadIdx.x;   // over 1280*128
  const int g = (int)(idx >> 7), j = (int)(idx & 127);
  const float* base = tmp0 + (long)g*1024;
  float t[8];
  #pragma unroll
  for (int c=0;c<8;c++) t[c] = base[c*128+j];
  const float bj = b0[j];
  #pragma unroll
  for (int i=0;i<8;i++){
    float s = bj;
    #pragma unroll
    for (int c=0;c<8;c++) s += ans[i*8+c]*t[c];
    g1[(long)g*1024 + i*128 + j] = (_Float16)fmaxf(s, 0.f);
  }
}

// ---------------------------------------------------------------------------
// K6: g2 mix + LN + node-mean -> emb (f16 out)
// ---------------------------------------------------------------------------
__global__ __launch_bounds__(128) void k_mix2(
  const float* __restrict__ tmp1, const float* __restrict__ An,
  const float* __restrict__ b1, const float* __restrict__ lng,
  const float* __restrict__ lnb, _Float16* __restrict__ emb)
{
  const int g = blockIdx.x, j = threadIdx.x;
  __shared__ float ans[64];
  __shared__ float g2s[8*128];
  __shared__ float stats[16];
  if (j<64) ans[j] = An[j];
  const float* base = tmp1 + (long)g*1024;
  float t[8];
  #pragma unroll
  for (int c=0;c<8;c++) t[c] = base[c*128 + j];
  const float bj = b1[j];
  __syncthreads();
  #pragma unroll
  for (int i=0;i<8;i++){
    float s = bj;
    #pragma unroll
    for (int c=0;c<8;c++) s += ans[i*8+c]*t[c];
    g2s[i*128+j] = s;
  }
  __syncthreads();
  {
    const int c = j>>4, l = j&15;
    float s=0.f, sq=0.f;
    for (int jj=l; jj<128; jj+=16){ float v=g2s[c*128+jj]; s+=v; sq+=v*v; }
    #pragma unroll
    for (int off=8; off>=1; off>>=1){ s += __shfl_xor(s, off); sq += __shfl_xor(sq, off); }
    if (l==0){
      float m = s*(1.f/128.f);
      stats[2*c] = m;
      stats[2*c+1] = rsqrtf(sq*(1.f/128.f) - m*m + 1e-5f);
    }
  }
  __syncthreads();
  float acc=0.f;
  #pragma unroll
  for (int i=0;i<8;i++) acc += (g2s[i*128+j] - stats[2*i]) * stats[2*i+1];
  emb[(long)g*128 + j] = (_Float16)(lng[j]*acc*0.125f + lnb[j]);
}

// ---------------------------------------------------------------------------
// K8: one LSTM layer, both directions. Block = (batch, dir), 1024 threads.
// Residency: rows jp 0..19 of each quarter in regs (80 VGPR); rows 20..31 of
// jg0/jg1 in LDS (96 KB); only jg2/jg3 stream rows 20..31 -> 96 KB/step.
// ---------------------------------------------------------------------------
__global__ __launch_bounds__(1024) void k_lstm(
    const float* __restrict__ xs,          // [1280][2048] fwd|rev gates
    const h2f16* __restrict__ wtf,         // [128][1024] packed j-pairs
    const h2f16* __restrict__ wtr,
    float* __restrict__ outf,              // [1280][512] (may be null)
    _Float16* __restrict__ outh)           // [1280][512] (may be null)
{
  const int S = 20;
  const int b = blockIdx.x >> 1, dir = blockIdx.x & 1;
  const h2f16* wt = dir ? wtr : wtf;
  __shared__ float part[4][1024];
  __shared__ _Float16 hsh[256];
  __shared__ __align__(16) unsigned char wlds[98304];   // rows 20..31 of jg0,jg1
  const int tid = threadIdx.x;
  const int jg = tid >> 8, r = tid & 255, grow = r*4;
  // reg-resident rows jp 0..19 of this thread's quarter (16B slice each)
  uint4 wreg[20];
  #pragma unroll
  for (int jp=0;jp<20;jp++)
    wreg[jp] = *reinterpret_cast<const uint4*>(
        reinterpret_cast<const unsigned int*>(wt + (long)(jg*32+jp)*1024 + grow));
  // LDS fill: rows 20..31 of quarter 0 (uint4 rows 20..31 -> idx 5120..8191)
  // then quarter 1 (rows 52..63 -> idx 13312..16383); row = 256 uint4.
  {
    const uint4* wsrc = reinterpret_cast<const uint4*>(wt);
    uint4* wdst = reinterpret_cast<uint4*>(wlds);
    for (int i=tid; i<6144; i+=1024){
      const int src = (i < 3072) ? (5120 + i) : (13312 + (i - 3072));
      wdst[i] = wsrc[src];
    }
  }
  if (tid < 256) hsh[tid] = (_Float16)0.f;
  float cc = 0.f;
  __syncthreads();
  const h2f16* hp2 = reinterpret_cast<const h2f16*>(hsh);
  for (int st=0; st<S; ++st){
    const int t = dir ? (S-1-st) : st;
    float a0=0.f,a1=0.f,a2=0.f,a3=0.f;
    #pragma unroll
    for (int jp=0; jp<20; ++jp){
      const h2f16 hv = hp2[jg*32 + jp];
      U4H w; w.u = wreg[jp];
      a0 = __builtin_amdgcn_fdot2(hv, w.h[0], a0, false);
      a1 = __builtin_amdgcn_fdot2(hv, w.h[1], a1, false);
      a2 = __builtin_amdgcn_fdot2(hv, w.h[2], a2, false);
      a3 = __builtin_amdgcn_fdot2(hv, w.h[3], a3, false);
    }
    if (jg < 2){
      #pragma unroll 6
      for (int jp=20; jp<32; ++jp){
        const h2f16 hv = hp2[jg*32 + jp];
        U4H w; w.u = *reinterpret_cast<const uint4*>(
            wlds + (long)(jg*12 + (jp-20))*4096 + grow*4);
        a0 = __builtin_amdgcn_fdot2(hv, w.h[0], a0, false);
        a1 = __builtin_amdgcn_fdot2(hv, w.h[1], a1, false);
        a2 = __builtin_amdgcn_fdot2(hv, w.h[2], a2, false);
        a3 = __builtin_amdgcn_fdot2(hv, w.h[3], a3, false);
      }
    } else {
      #pragma unroll 6
      for (int jp=20; jp<32; ++jp){
        const h2f16 hv = hp2[jg*32 + jp];
        U4H w; w.u = *reinterpret_cast<const uint4*>(
            reinterpret_cast<const unsigned int*>(wt + (long)(jg*32+jp)*1024 + grow));
        a0 = __builtin_amdgcn_fdot2(hv, w.h[0], a0, false);
        a1 = __builtin_amdgcn_fdot2(hv, w.h[1], a1, false);
        a2 = __builtin_amdgcn_fdot2(hv, w.h[2], a2, false);
        a3 = __builtin_amdgcn_fdot2(hv, w.h[3], a3, false);
      }
    }
    *reinterpret_cast<float4*>(&part[jg][grow]) = make_float4(a0,a1,a2,a3);
    __syncthreads();
    if (tid < 256){
      const float* xrow = xs + ((long)b*S + t)*2048 + dir*1024;
      float g0 = xrow[tid]
               + (part[0][tid]      + part[1][tid])      + (part[2][tid]      + part[3][tid]);
      float g1 = xrow[256+tid]
               + (part[0][256+tid]  + part[1][256+tid])  + (part[2][256+tid]  + part[3][256+tid]);
      float g2 = xrow[512+tid]
               + (part[0][512+tid]  + part[1][512+tid])  + (part[2][512+tid]  + part[3][512+tid]);
      float g3 = xrow[768+tid]
               + (part[0][768+tid]  + part[1][768+tid])  + (part[2][768+tid]  + part[3][768+tid]);
      cc = sigf(g1)*cc + sigf(g0)*tanh_f(g2);
      const float h = sigf(g3)*tanh_f(cc);
      hsh[tid] = (_Float16)h;
      const long o = ((long)b*S + t)*512 + dir*256 + tid;
      if (outf) outf[o] = h;
      if (outh) outh[o] = (_Float16)h;
    }
    __syncthreads();
  }
}

// ---------------------------------------------------------------------------
// K11: final LayerNorm(512) + classifier (5) per row
// ---------------------------------------------------------------------------
__global__ __launch_bounds__(128) void k_lncls(
  const float* __restrict__ in, const float* __restrict__ g,
  const float* __restrict__ b, const float* __restrict__ cw,
  const float* __restrict__ cb, float* __restrict__ out)
{
  const int row = blockIdx.x, tid = threadIdx.x;
  __shared__ float sred[4];
  __shared__ float cred[2][5];
  float4 v = *reinterpret_cast<const float4*>(in + (long)row*512 + tid*4);
  float s  = v.x+v.y+v.z+v.w;
  float sq = v.x*v.x+v.y*v.y+v.z*v.z+v.w*v.w;
  #pragma unroll
  for (int off=32; off>=1; off>>=1){ s += __shfl_xor(s, off); sq += __shfl_xor(sq, off); }
  const int wv = tid>>6;
  if ((tid&63)==0){ sred[wv*2]=s; sred[wv*2+1]=sq; }
  __syncthreads();
  const float S = sred[0]+sred[2], SQ = sred[1]+sred[3];
  const float m = S*(1.f/512.f);
  const float rstd = rsqrtf(SQ*(1.f/512.f) - m*m + 1e-5f);
  float4 gg = *reinterpret_cast<const float4*>(g + tid*4);
  float4 bb = *reinterpret_cast<const float4*>(b + tid*4);
  const float n0 = (v.x-m)*rstd*gg.x + bb.x;
  const float n1 = (v.y-m)*rstd*gg.y + bb.y;
  const float n2 = (v.z-m)*rstd*gg.z + bb.z;
  const float n3 = (v.w-m)*rstd*gg.w + bb.w;
  #pragma unroll
  for (int nc=0; nc<5; ++nc){
    float4 w = *reinterpret_cast<const float4*>(cw + nc*512 + tid*4);
    float p = n0*w.x + n1*w.y + n2*w.z + n3*w.w;
    #pragma unroll
    for (int off=32; off>=1; off>>=1) p += __shfl_xor(p, off);
    if ((tid&63)==0) cred[wv][nc] = p;
  }
  __syncthreads();
  if (tid < 5) out[(long)row*5 + tid] = cred[0][tid] + cred[1][tid] + cb[tid];
}

// ---------------------------------------------------------------------------
extern "C" void kernel_launch(void* const* d_in, const int* in_sizes, int n_in,
                              void* d_out, int out_size, void* d_ws, size_t ws_size,
                              hipStream_t stream)
{
  const float* x     = (const float*)d_in[0];
  const int*   ei    = (const int*)d_in[1];
  const float* w1    = (const float*)d_in[2];
  const float* c1b   = (const float*)d_in[3];
  const float* bg1   = (const float*)d_in[4];
  const float* bb1   = (const float*)d_in[5];
  const float* w2    = (const float*)d_in[6];
  const float* c2b   = (const float*)d_in[7];
  const float* bg2   = (const float*)d_in[8];
  const float* bb2   = (const float*)d_in[9];
  const float* w3    = (const float*)d_in[10];
  const float* c3b   = (const float*)d_in[11];
  const float* bg3   = (const float*)d_in[12];
  const float* bb3   = (const float*)d_in[13];
  const float* gcn0w = (const float*)d_in[14];
  const float* gcn0b = (const float*)d_in[15];
  const float* gcn1w = (const float*)d_in[16];
  const float* gcn1b = (const float*)d_in[17];
  const float* lng   = (const float*)d_in[18];
  const float* lnb   = (const float*)d_in[19];
  const float* wih0  = (const float*)d_in[20];
  const float* whh0  = (const float*)d_in[21];
  const float* bih0  = (const float*)d_in[22];
  const float* bhh0  = (const float*)d_in[23];
  const float* wih0r = (const float*)d_in[24];
  const float* whh0r = (const float*)d_in[25];
  const float* bih0r = (const float*)d_in[26];
  const float* bhh0r = (const float*)d_in[27];
  const float* wih1  = (const float*)d_in[28];
  const float* whh1  = (const float*)d_in[29];
  const float* bih1  = (const float*)d_in[30];
  const float* bhh1  = (const float*)d_in[31];
  const float* wih1r = (const float*)d_in[32];
  const float* whh1r = (const float*)d_in[33];
  const float* bih1r = (const float*)d_in[34];
  const float* bhh1r = (const float*)d_in[35];
  const float* lstmg = (const float*)d_in[36];
  const float* lstmb = (const float*)d_in[37];
  const float* clsw  = (const float*)d_in[38];
  const float* clsb  = (const float*)d_in[39];
  float* ws  = (float*)d_ws;
  float* out = (float*)d_out;

  // workspace layout (float offsets), ~23.5 MB total
  float*    An      = ws + 0;                         // 64
  _Float16* bw2f    = (_Float16*)(ws + 64);           // 3072 h
  _Float16* bw3f    = (_Float16*)(ws + 1600);         // 6144 h
  _Float16* feats16 = (_Float16*)(ws + 4672);         // 655360 h
  _Float16* g1b16   = (_Float16*)(ws + 332352);       // 1310720 h
  _Float16* emb16   = (_Float16*)(ws + 987712);       // 163840 h
  _Float16* l0h     = (_Float16*)(ws + 1069632);      // 655360 h
  _Float16* w0f     = (_Float16*)(ws + 1397312);      // 131072 h
  _Float16* w0rf    = (_Float16*)(ws + 1462848);      // 131072 h
  _Float16* w1f     = (_Float16*)(ws + 1528384);      // 524288 h
  _Float16* w1rf    = (_Float16*)(ws + 1790528);      // 524288 h
  _Float16* gw0f    = (_Float16*)(ws + 2052672);      // 8192 h
  _Float16* gw1f    = (_Float16*)(ws + 2056768);      // 16384 h
  h2f16*    wt0f    = (h2f16*)(ws + 2064960);         // 131072 f each
  h2f16*    wt0r    = (h2f16*)(ws + 2196032);
  h2f16*    wt1f    = (h2f16*)(ws + 2327104);
  h2f16*    wt1r    = (h2f16*)(ws + 2458176);
  float*    l1f     = ws + 2589248;                   // 655360 f
  float*    xs      = ws + 3244608;                   // 2621440 f
  float*    tmp     = xs;                             // aliases xs

  // Stage 0: fused prep (adjacency + all weight packs/transposes)
  k_prep<<<7289, 256, 0, stream>>>(ei, An, w2, w3, bg2, bg3, bw2f, bw3f,
                                   wih0, wih0r, wih1, wih1r, gcn0w, gcn1w,
                                   w0f, w0rf, w1f, w1rf, gw0f, gw1f,
                                   whh0, whh0r, whh1, whh1r,
                                   wt0f, wt0r, wt1f, wt1r);
  // Stage 1: conv front-end
  k_conv<<<10240, 512, 0, stream>>>(x, w1,c1b,bg1,bb1, bw2f,c2b,bg2,bb2,
                                    bw3f,c3b,bg3,bb3, feats16);

  // Stage 2: GCN
  k_gemm_mf<<<dim3(2, 160), 256, 0, stream>>>(feats16, gw0f, nullptr, nullptr, tmp, 10240, 128, 64, 128);
  k_mix1<<<640,256,0,stream>>>(tmp, An, gcn0b, g1b16);
  k_gemm_mf<<<dim3(2, 160), 256, 0, stream>>>(g1b16, gw1f, nullptr, nullptr, tmp, 10240, 128, 128, 128);
  k_mix2<<<1280,128,0,stream>>>(tmp, An, gcn1b, lng, lnb, emb16);

  // Stage 3: BiLSTM layer 0
  k_gemm_mf2<<<dim3(16, 20, 2), 256, 0, stream>>>(emb16, w0f, w0rf,
      bih0, bhh0, bih0r, bhh0r, xs, 1024, 1280, 1024, 128, 2048);
  k_lstm<<<128, 1024, 0, stream>>>(xs, wt0f, wt0r, nullptr, l0h);

  // BiLSTM layer 1
  k_gemm_mf2<<<dim3(16, 20, 2), 256, 0, stream>>>(l0h, w1f, w1rf,
      bih1, bhh1, bih1r, bhh1r, xs, 1024, 1280, 1024, 512, 2048);
  k_lstm<<<128, 1024, 0, stream>>>(xs, wt1f, wt1r, l1f, nullptr);

  // Stage 4: LN + classifier
  k_lncls<<<1280, 128, 0, stream>>>(l1f, lstmg, lstmb, clsw, clsb, out);
}

// Round 12
// 293.118 us; speedup vs baseline: 1.1150x; 1.1150x over previous
//
#include <hip/hip_runtime.h>
#include <hip/hip_bf16.h>

#define DEVI __device__ __forceinline__

typedef _Float16 h2f16 __attribute__((ext_vector_type(2)));
typedef _Float16 f16x4 __attribute__((ext_vector_type(4)));
typedef _Float16 f16x8 __attribute__((ext_vector_type(8)));
typedef float    f32x4 __attribute__((ext_vector_type(4)));
union U4H { uint4 u; h2f16 h[4]; };
union F8  { f16x8 v8; f16x4 v4[2]; };

DEVI float sigf(float x){ return 1.f/(1.f + __expf(-x)); }
DEVI float tanh_f(float x){
  float ax = fabsf(x);
  float e = __expf(-2.f*ax);
  float t = (1.f - e)/(1.f + e);
  return copysignf(t, x);
}
DEVI h2f16 hmax2(h2f16 a, h2f16 b){
  h2f16 r; r[0] = a[0] > b[0] ? a[0] : b[0]; r[1] = a[1] > b[1] ? a[1] : b[1]; return r;
}

// ---------------------------------------------------------------------------
// K0: fused prep. bid 0: adjacency; 1..24: conv w pack; 25..5240: GEMM w pack;
// 5241..7288: w_hh transpose+pack (4 matrices).
// ---------------------------------------------------------------------------
__global__ __launch_bounds__(256) void k_prep(
  const int* __restrict__ ei, float* __restrict__ An,
  const float* __restrict__ w2, const float* __restrict__ w3,
  const float* __restrict__ bg2, const float* __restrict__ bg3,
  _Float16* __restrict__ bw2f, _Float16* __restrict__ bw3f,
  const float* __restrict__ a0, const float* __restrict__ a1,
  const float* __restrict__ a2, const float* __restrict__ a3,
  const float* __restrict__ a4, const float* __restrict__ a5,
  _Float16* __restrict__ o0, _Float16* __restrict__ o1,
  _Float16* __restrict__ o2, _Float16* __restrict__ o3,
  _Float16* __restrict__ o4, _Float16* __restrict__ o5,
  const float* __restrict__ whh0, const float* __restrict__ whh0r,
  const float* __restrict__ whh1, const float* __restrict__ whh1r,
  h2f16* __restrict__ wt0f, h2f16* __restrict__ wt0r,
  h2f16* __restrict__ wt1f, h2f16* __restrict__ wt1r)
{
  const int bid = blockIdx.x, tid = threadIdx.x;
  if (bid == 0){
    __shared__ float A[64];
    __shared__ float dinv[8];
    if (tid<64) A[tid] = ((tid>>3)==(tid&7)) ? 1.f : 0.f;
    __syncthreads();
    if (tid==0){
      for (int e=0;e<56;e++){ int s=ei[e], d=ei[56+e]; A[d*8+s] += 1.f; }
    }
    __syncthreads();
    if (tid<8){ float s=0.f; for (int j=0;j<8;j++) s+=A[tid*8+j]; dinv[tid]=rsqrtf(s); }
    __syncthreads();
    if (tid<64) An[tid] = A[tid]*dinv[tid>>3]*dinv[tid&7];
    return;
  }
  if (bid <= 24){
    const int i = (bid-1)*256 + tid;
    const float rs = rsqrtf(1.f+1e-5f);
    if (i < 3072){
      const int j = i&7, m = (i>>3)&15, g = (i>>7)&3, nt = (i>>9)&1, s = i>>10;
      const int kk = 32*s + 8*g + j;
      const int k = kk >> 4, ic = kk & 15, oc = nt*16 + m;
      bw2f[i] = (_Float16)((k < 5 ? w2[oc*80 + ic*5 + k] : 0.f) * (bg2[oc]*rs));
    }
    if (i < 6144){
      const int j = i&7, m = (i>>3)&15, g = (i>>7)&3, wv = (i>>9)&3, s = i>>11;
      const int kk = 32*s + 8*g + j;
      const int k = kk >> 5, ic = kk & 31, oc = wv*16 + m;
      bw3f[i] = (_Float16)(w3[oc*96 + ic*3 + k] * (bg3[oc]*rs));
    }
    return;
  }
  if (bid <= 5240){
    const int i = (bid-25)*256 + tid;
    if      (i <  131072) o0[i] = (_Float16)a0[i];
    else if (i <  262144) o1[i-131072] = (_Float16)a1[i-131072];
    else if (i <  786432) o2[i-262144] = (_Float16)a2[i-262144];
    else if (i < 1310720) o3[i-786432] = (_Float16)a3[i-786432];
    else if (i < 1318912) o4[i-1310720] = (_Float16)a4[i-1310720];
    else if (i < 1335296) o5[i-1318912] = (_Float16)a5[i-1318912];
    return;
  }
  {
    const int idx = (bid-5241)*256 + tid;        // [0, 524288)
    const int which = idx >> 17, i = idx & 131071;
    const int g = i & 1023, jp = i >> 10;
    const float* in = (which==0) ? whh0 : (which==1) ? whh0r : (which==2) ? whh1 : whh1r;
    h2f16* outp    = (which==0) ? wt0f : (which==1) ? wt0r  : (which==2) ? wt1f : wt1r;
    h2f16 p;
    p[0] = (_Float16)in[g*256 + 2*jp];
    p[1] = (_Float16)in[g*256 + 2*jp + 1];
    outp[(long)jp*1024 + g] = p;
  }
}

// ---------------------------------------------------------------------------
// K1: fused conv front-end, 512 threads (8 waves), 4 blocks/CU. (r11 version)
// ---------------------------------------------------------------------------
__global__ __launch_bounds__(512,8) void k_conv(
    const float* __restrict__ x,
    const float* __restrict__ w1g, const float* __restrict__ c1b,
    const float* __restrict__ bg1, const float* __restrict__ bb1,
    const _Float16* __restrict__ bw2f,
    const float* __restrict__ c2b, const float* __restrict__ bg2, const float* __restrict__ bb2,
    const _Float16* __restrict__ bw3f,
    const float* __restrict__ c3b, const float* __restrict__ bg3, const float* __restrict__ bb3,
    _Float16* __restrict__ feats)
{
  __shared__ __align__(16) unsigned char smb[38592];
  __shared__ h2f16 w1p[16][4];
  __shared__ float kb1o[16], kb2o[32], kb3o[64];
  __shared__ float redc[8][16];
  h2f16* sxh = reinterpret_cast<h2f16*>(smb + 20160);
  const int tid = threadIdx.x;
  const long sig = blockIdx.x;
  const float* xg = x + sig*3000;

  {
    const float4* xg4 = reinterpret_cast<const float4*>(xg);
    for (int i=tid; i<750; i+=512){
      float4 v = xg4[i];
      h2f16 p0; p0[0]=(_Float16)v.x; p0[1]=(_Float16)v.y;
      h2f16 p1; p1[0]=(_Float16)v.z; p1[1]=(_Float16)v.w;
      sxh[2*i+2] = p0; sxh[2*i+3] = p1;
    }
    if (tid<3){
      h2f16 z; z[0]=(_Float16)0.f; z[1]=(_Float16)0.f;
      sxh[tid<2 ? tid : 1502] = z;
    }
    if (tid<32){
      const int rr = tid>>3, cp = tid&7;
      const int row = (rr<2) ? rr : (500+rr);
      h2f16 z; z[0]=(_Float16)0.f; z[1]=(_Float16)0.f;
      *reinterpret_cast<h2f16*>(smb + row*40 + 4*cp) = z;
    }
    const float rs = rsqrtf(1.f+1e-5f);
    if (tid<64){
      const int c = tid>>2, j = tid&3;
      const float s = bg1[c]*rs;
      h2f16 p;
      if (j==0){ p[0]=(_Float16)0.f; p[1]=(_Float16)(w1g[c*7+0]*s); }
      else     { p[0]=(_Float16)(w1g[c*7+2*j-1]*s); p[1]=(_Float16)(w1g[c*7+2*j]*s); }
      w1p[c][j] = p;
    }
    if (tid<16) kb1o[tid] = c1b[tid]*(bg1[tid]*rs) + bb1[tid];
    if (tid<32) kb2o[tid] = c2b[tid]*(bg2[tid]*rs) + bb2[tid];
    if (tid<64) kb3o[tid] = c3b[tid]*(bg3[tid]*rs) + bb3[tid];
  }
  __syncthreads();

  // Phase A
  {
    const int cp = tid & 7;
    h2f16 wpa[4], wpb[4];
    #pragma unroll
    for (int j=0;j<4;j++){ wpa[j] = w1p[2*cp][j]; wpb[j] = w1p[2*cp+1][j]; }
    const float oa = kb1o[2*cp], ob = kb1o[2*cp+1];
    for (int u = tid>>3; u<500; u+=64){
      h2f16 xq[6];
      #pragma unroll
      for (int r=0;r<6;r++) xq[r] = sxh[3*u + r];
      float a0=0.f,a1=0.f,a2=0.f,b0=0.f,b1=0.f,b2=0.f;
      #pragma unroll
      for (int j=0;j<4;j++){
        a0 = __builtin_amdgcn_fdot2(xq[j],   wpa[j], a0, false);
        a1 = __builtin_amdgcn_fdot2(xq[j+1], wpa[j], a1, false);
        a2 = __builtin_amdgcn_fdot2(xq[j+2], wpa[j], a2, false);
        b0 = __builtin_amdgcn_fdot2(xq[j],   wpb[j], b0, false);
        b1 = __builtin_amdgcn_fdot2(xq[j+1], wpb[j], b1, false);
        b2 = __builtin_amdgcn_fdot2(xq[j+2], wpb[j], b2, false);
      }
      const float ya = fmaxf(fmaxf(fmaxf(a0,a1),a2) + oa, 0.f);
      const float yb = fmaxf(fmaxf(fmaxf(b0,b1),b2) + ob, 0.f);
      h2f16 p; p[0]=(_Float16)ya; p[1]=(_Float16)yb;
      *reinterpret_cast<h2f16*>(smb + (u+2)*40 + 4*cp) = p;
    }
  }
  __syncthreads();

  const int wv = tid >> 6, lane = tid & 63;
  const int m = lane & 15, g = lane >> 4;

  // Phase B
  {
    const int nt = wv & 1;
    f16x8 bf[3];
    #pragma unroll
    for (int s=0;s<3;s++)
      bf[s] = *reinterpret_cast<const f16x8*>(&bw2f[(((s*2+nt)*4+g)*16+m)*8]);
    const int oc = nt*16 + m;
    const float of = kb2o[oc];
    #pragma unroll
    for (int i=0;i<4;i++){
      const int mt = (wv>>1) + 4*i;
      const int trow = mt*16 + m;
      f32x4 acc = {0.f,0.f,0.f,0.f};
      #pragma unroll
      for (int s=0;s<3;s++){
        const int kk = 32*s + 8*g;
        const int k = kk >> 4;
        const int ab = 80*trow + 40*k + 16*(g&1);
        F8 a;
        a.v4[0] = *reinterpret_cast<const f16x4*>(smb + ab);
        a.v4[1] = *reinterpret_cast<const f16x4*>(smb + ab + 8);
        acc = __builtin_amdgcn_mfma_f32_16x16x32_f16(a.v8, bf[s], acc, 0,0,0);
      }
      #pragma unroll
      for (int r=0;r<4;r++){
        const int t = mt*16 + 4*g + r;
        const float z = fmaxf(acc[r] + of, 0.f);
        *reinterpret_cast<_Float16*>(smb + 20160 + t*72 + 2*oc) = (_Float16)z;
      }
    }
  }
  __syncthreads();

  // Pool
  {
    if (tid < 240){
      const int rr = tid >> 4, cc = tid & 15;
      const int row = (rr == 0) ? 0 : (83 + rr);
      h2f16 z; z[0]=(_Float16)0.f; z[1]=(_Float16)0.f;
      *reinterpret_cast<h2f16*>(smb + row*80 + 4*cc) = z;
    }
    for (int i=tid; i<1328; i+=512){
      const int u = i >> 4, cc = i & 15;
      h2f16 a = *reinterpret_cast<const h2f16*>(smb + 20160 + (3*u)*72 + 4*cc);
      h2f16 b = *reinterpret_cast<const h2f16*>(smb + 20160 + (3*u+1)*72 + 4*cc);
      h2f16 c = *reinterpret_cast<const h2f16*>(smb + 20160 + (3*u+2)*72 + 4*cc);
      *reinterpret_cast<h2f16*>(smb + (u+1)*80 + 4*cc) = hmax2(hmax2(a,b), c);
    }
  }
  __syncthreads();

  // Phase C
  {
    const int nt = wv & 3;
    f16x8 bf[3];
    #pragma unroll
    for (int s=0;s<3;s++)
      bf[s] = *reinterpret_cast<const f16x8*>(&bw3f[(((s*4+nt)*4+g)*16+m)*8]);
    const int oc = nt*16 + m;
    const float of = kb3o[oc];
    float macc = 0.f;
    #pragma unroll
    for (int q=0;q<3;q++){
      const int mt = (wv>>2) + 2*q;
      const int trow = mt*16 + m;
      f32x4 acc = {0.f,0.f,0.f,0.f};
      #pragma unroll
      for (int s=0;s<3;s++){
        f16x8 af = *reinterpret_cast<const f16x8*>(smb + (trow + s)*80 + 16*g);
        acc = __builtin_amdgcn_mfma_f32_16x16x32_f16(af, bf[s], acc, 0,0,0);
      }
      #pragma unroll
      for (int r=0;r<4;r++){
        const int t = mt*16 + 4*g + r;
        if (t < 83) macc += fmaxf(acc[r] + of, 0.f);
      }
    }
    macc += __shfl_xor(macc, 16);
    macc += __shfl_xor(macc, 32);
    if (lane < 16) redc[wv][m] = macc;
  }
  __syncthreads();
  if (tid < 64)
    feats[sig*64 + tid] = (_Float16)((redc[tid>>4][tid&15] + redc[(tid>>4)+4][tid&15]) * (1.f/83.f));
}

// ---------------------------------------------------------------------------
// K2: GCN layer 1 fused: C = X@W^T (MFMA), then g1 = relu(An-mix + b0), f16.
// Tile 64 rows x 64 cols, K param. grid (N/64, M/64).
// ---------------------------------------------------------------------------
__global__ __launch_bounds__(256) void k_gcn1(
  const _Float16* __restrict__ X, const _Float16* __restrict__ W,
  const float* __restrict__ An, const float* __restrict__ b0,
  _Float16* __restrict__ g1, int K)
{
  __shared__ __align__(16) unsigned char lds[17408];   // Xs|Ws during loop; Cs after
  __shared__ float ans[64];
  unsigned char* Xs = lds;
  unsigned char* Ws = lds + 4608;
  float* Cs = reinterpret_cast<float*>(lds);
  const int tid = threadIdx.x;
  const int m0 = blockIdx.y*64, n0 = blockIdx.x*64;
  const int wv = tid>>6, lane = tid&63, m = lane&15, g = lane>>4;
  const int sr = tid>>2, sq = tid&3;
  if (tid<64) ans[tid] = An[tid];
  f32x4 acc[4] = {{0.f,0.f,0.f,0.f},{0.f,0.f,0.f,0.f},{0.f,0.f,0.f,0.f},{0.f,0.f,0.f,0.f}};
  for (int k0=0; k0<K; k0+=32){
    uint4 xa = *reinterpret_cast<const uint4*>(X + (long)(m0+sr)*K + k0 + sq*8);
    uint4 wa = *reinterpret_cast<const uint4*>(W + (long)(n0+sr)*K + k0 + sq*8);
    __syncthreads();
    *reinterpret_cast<uint4*>(Xs + sr*72 + sq*16) = xa;
    *reinterpret_cast<uint4*>(Ws + sr*72 + sq*16) = wa;
    __syncthreads();
    f16x8 af = *reinterpret_cast<const f16x8*>(Xs + (wv*16+m)*72 + g*16);
    #pragma unroll
    for (int nt=0;nt<4;nt++){
      f16x8 bf = *reinterpret_cast<const f16x8*>(Ws + (nt*16+m)*72 + g*16);
      acc[nt] = __builtin_amdgcn_mfma_f32_16x16x32_f16(af, bf, acc[nt], 0,0,0);
    }
  }
  __syncthreads();
  #pragma unroll
  for (int nt=0;nt<4;nt++)
    #pragma unroll
    for (int r=0;r<4;r++)
      Cs[(wv*16 + g*4 + r)*68 + nt*16 + m] = acc[nt][r];
  __syncthreads();
  for (int idx=tid; idx<512; idx+=256){
    const int gg = idx>>6, j = idx&63;
    float t[8];
    #pragma unroll
    for (int c=0;c<8;c++) t[c] = Cs[(gg*8+c)*68 + j];
    const float bj = b0[n0+j];
    #pragma unroll
    for (int i=0;i<8;i++){
      float s = bj;
      #pragma unroll
      for (int c=0;c<8;c++) s += ans[i*8+c]*t[c];
      g1[(long)(m0 + gg*8 + i)*128 + n0 + j] = (_Float16)fmaxf(s, 0.f);
    }
  }
}

// ---------------------------------------------------------------------------
// K2b: GCN layer 2 fused: C = X@W^T (64x128 tile, full N), An-mix + b1,
// LN per node row, mean over 8 nodes -> emb (f16). grid = M/64 = 160.
// ---------------------------------------------------------------------------
__global__ __launch_bounds__(256) void k_gcn2(
  const _Float16* __restrict__ X, const _Float16* __restrict__ W,
  const float* __restrict__ An, const float* __restrict__ b1,
  const float* __restrict__ lng, const float* __restrict__ lnb,
  _Float16* __restrict__ emb)
{
  __shared__ __align__(16) unsigned char lds[33792];   // Xs|Ws loop; Cs 64x132 f32
  __shared__ float ans[64];
  unsigned char* Xs = lds;
  unsigned char* Ws = lds + 4608;
  float* Cs = reinterpret_cast<float*>(lds);
  const int tid = threadIdx.x;
  const int m0 = blockIdx.x*64;
  const int wv = tid>>6, lane = tid&63, m = lane&15, g = lane>>4;
  const int sr = tid>>2, sq = tid&3;
  if (tid<64) ans[tid] = An[tid];
  f32x4 acc[8] = {};
  for (int k0=0; k0<128; k0+=32){
    uint4 xa = *reinterpret_cast<const uint4*>(X + (long)(m0+sr)*128 + k0 + sq*8);
    uint4 wa0 = *reinterpret_cast<const uint4*>(W + (long)(tid>>1)*128 + k0 + (tid&1)*16);
    uint4 wa1 = *reinterpret_cast<const uint4*>(W + (long)(tid>>1)*128 + k0 + (tid&1)*16 + 8);
    __syncthreads();
    *reinterpret_cast<uint4*>(Xs + sr*72 + sq*16) = xa;
    *reinterpret_cast<uint4*>(Ws + (tid>>1)*72 + (tid&1)*32) = wa0;
    *reinterpret_cast<uint4*>(Ws + (tid>>1)*72 + (tid&1)*32 + 16) = wa1;
    __syncthreads();
    f16x8 af = *reinterpret_cast<const f16x8*>(Xs + (wv*16+m)*72 + g*16);
    #pragma unroll
    for (int nt=0;nt<8;nt++){
      f16x8 bf = *reinterpret_cast<const f16x8*>(Ws + (nt*16+m)*72 + g*16);
      acc[nt] = __builtin_amdgcn_mfma_f32_16x16x32_f16(af, bf, acc[nt], 0,0,0);
    }
  }
  __syncthreads();
  #pragma unroll
  for (int nt=0;nt<8;nt++)
    #pragma unroll
    for (int r=0;r<4;r++)
      Cs[(wv*16 + g*4 + r)*132 + nt*16 + m] = acc[nt][r];
  __syncthreads();
  // epilogue: 8 samples x 32 lanes; lane owns cols l, l+32, l+64, l+96
  {
    const int s = tid>>5, l = tid&31;
    float g2v[8][4];
    #pragma unroll
    for (int jj=0;jj<4;jj++){
      const int j = l + jj*32;
      float t[8];
      #pragma unroll
      for (int c=0;c<8;c++) t[c] = Cs[(s*8+c)*132 + j];
      const float bj = b1[j];
      #pragma unroll
      for (int i=0;i<8;i++){
        float v = bj;
        #pragma unroll
        for (int c=0;c<8;c++) v += ans[i*8+c]*t[c];
        g2v[i][jj] = v;
      }
    }
    float mi[8], ri[8];
    #pragma unroll
    for (int i=0;i<8;i++){
      float sm=0.f, sq2=0.f;
      #pragma unroll
      for (int jj=0;jj<4;jj++){ sm += g2v[i][jj]; sq2 += g2v[i][jj]*g2v[i][jj]; }
      #pragma unroll
      for (int off=16; off>=1; off>>=1){ sm += __shfl_xor(sm, off); sq2 += __shfl_xor(sq2, off); }
      const float mu = sm*(1.f/128.f);
      mi[i] = mu;
      ri[i] = rsqrtf(sq2*(1.f/128.f) - mu*mu + 1e-5f);
    }
    #pragma unroll
    for (int jj=0;jj<4;jj++){
      const int j = l + jj*32;
      float a = 0.f;
      #pragma unroll
      for (int i=0;i<8;i++) a += (g2v[i][jj]-mi[i])*ri[i];
      emb[(long)(blockIdx.x*8 + s)*128 + j] = (_Float16)(lng[j]*a*0.125f + lnb[j]);
    }
  }
}

// ---------------------------------------------------------------------------
// K3b: dual-W MFMA GEMM: blockIdx.z selects (Wa,b1a,b2a,C) vs (Wb,b1b,b2b,C+co)
// ---------------------------------------------------------------------------
__global__ __launch_bounds__(256) void k_gemm_mf2(
  const _Float16* __restrict__ X,
  const _Float16* __restrict__ Wa, const _Float16* __restrict__ Wb,
  const float* __restrict__ b1a, const float* __restrict__ b2a,
  const float* __restrict__ b1b, const float* __restrict__ b2b,
  float* __restrict__ C, int co, int M, int N, int K, int ldc)
{
  __shared__ __align__(16) unsigned char lds[128*72];
  unsigned char* Xs = lds;
  unsigned char* Ws = lds + 64*72;
  const int z = blockIdx.z;
  const _Float16* W = z ? Wb : Wa;
  const float* b1 = z ? b1b : b1a;
  const float* b2 = z ? b2b : b2a;
  float* Cz = C + (z ? co : 0);
  const int tid = threadIdx.x;
  const int m0 = blockIdx.y*64, n0 = blockIdx.x*64;
  const int wv = tid>>6, lane = tid&63, m = lane&15, g = lane>>4;
  const int sr = tid>>2, sq = tid&3;
  f32x4 acc[4] = {{0.f,0.f,0.f,0.f},{0.f,0.f,0.f,0.f},{0.f,0.f,0.f,0.f},{0.f,0.f,0.f,0.f}};
  for (int k0=0; k0<K; k0+=32){
    uint4 xa = *reinterpret_cast<const uint4*>(X + (long)(m0+sr)*K + k0 + sq*8);
    uint4 wa = *reinterpret_cast<const uint4*>(W + (long)(n0+sr)*K + k0 + sq*8);
    __syncthreads();
    *reinterpret_cast<uint4*>(Xs + sr*72 + sq*16) = xa;
    *reinterpret_cast<uint4*>(Ws + sr*72 + sq*16) = wa;
    __syncthreads();
    f16x8 af = *reinterpret_cast<const f16x8*>(Xs + (wv*16+m)*72 + g*16);
    #pragma unroll
    for (int nt=0;nt<4;nt++){
      f16x8 bf = *reinterpret_cast<const f16x8*>(Ws + (nt*16+m)*72 + g*16);
      acc[nt] = __builtin_amdgcn_mfma_f32_16x16x32_f16(af, bf, acc[nt], 0,0,0);
    }
  }
  #pragma unroll
  for (int nt=0;nt<4;nt++){
    const int col = n0 + nt*16 + m;
    float bias = b1[col] + b2[col];
    #pragma unroll
    for (int r=0;r<4;r++)
      Cz[(long)(m0 + wv*16 + g*4 + r)*ldc + col] = acc[nt][r] + bias;
  }
}

// ---------------------------------------------------------------------------
// K8: one LSTM layer, both directions. Block = (batch, dir), 1024 threads.
// (r10 configuration: wreg[16], rows 16..31 of jg0/jg1 in 128KB LDS.)
// ---------------------------------------------------------------------------
__global__ __launch_bounds__(1024) void k_lstm(
    const float* __restrict__ xs,          // [1280][2048] fwd|rev gates
    const h2f16* __restrict__ wtf,         // [128][1024] packed j-pairs
    const h2f16* __restrict__ wtr,
    float* __restrict__ outf,              // [1280][512] (may be null)
    _Float16* __restrict__ outh)           // [1280][512] (may be null)
{
  const int S = 20;
  const int b = blockIdx.x >> 1, dir = blockIdx.x & 1;
  const h2f16* wt = dir ? wtr : wtf;
  __shared__ float part[4][1024];
  __shared__ _Float16 hsh[256];
  __shared__ __align__(16) unsigned char wlds[131072];   // rows 16..31 of jg0,jg1
  const int tid = threadIdx.x;
  const int jg = tid >> 8, r = tid & 255, grow = r*4;
  uint4 wreg[16];
  #pragma unroll
  for (int jp=0;jp<16;jp++)
    wreg[jp] = *reinterpret_cast<const uint4*>(
        reinterpret_cast<const unsigned int*>(wt + (long)(jg*32+jp)*1024 + grow));
  {
    const uint4* wsrc = reinterpret_cast<const uint4*>(wt);
    uint4* wdst = reinterpret_cast<uint4*>(wlds);
    for (int i=tid; i<8192; i+=1024){
      const int src = (i < 4096) ? (4096 + i) : (12288 + (i - 4096));
      wdst[i] = wsrc[src];
    }
  }
  if (tid < 256) hsh[tid] = (_Float16)0.f;
  float cc = 0.f;
  __syncthreads();
  const h2f16* hp2 = reinterpret_cast<const h2f16*>(hsh);
  for (int st=0; st<S; ++st){
    const int t = dir ? (S-1-st) : st;
    float a0=0.f,a1=0.f,a2=0.f,a3=0.f;
    #pragma unroll
    for (int jp=0; jp<16; ++jp){
      const h2f16 hv = hp2[jg*32 + jp];
      U4H w; w.u = wreg[jp];
      a0 = __builtin_amdgcn_fdot2(hv, w.h[0], a0, false);
      a1 = __builtin_amdgcn_fdot2(hv, w.h[1], a1, false);
      a2 = __builtin_amdgcn_fdot2(hv, w.h[2], a2, false);
      a3 = __builtin_amdgcn_fdot2(hv, w.h[3], a3, false);
    }
    if (jg < 2){
      #pragma unroll 8
      for (int jp=16; jp<32; ++jp){
        const h2f16 hv = hp2[jg*32 + jp];
        U4H w; w.u = *reinterpret_cast<const uint4*>(
            wlds + (long)(jg*16 + (jp-16))*4096 + grow*4);
        a0 = __builtin_amdgcn_fdot2(hv, w.h[0], a0, false);
        a1 = __builtin_amdgcn_fdot2(hv, w.h[1], a1, false);
        a2 = __builtin_amdgcn_fdot2(hv, w.h[2], a2, false);
        a3 = __builtin_amdgcn_fdot2(hv, w.h[3], a3, false);
      }
    } else {
      #pragma unroll 8
      for (int jp=16; jp<32; ++jp){
        const h2f16 hv = hp2[jg*32 + jp];
        U4H w; w.u = *reinterpret_cast<const uint4*>(
            reinterpret_cast<const unsigned int*>(wt + (long)(jg*32+jp)*1024 + grow));
        a0 = __builtin_amdgcn_fdot2(hv, w.h[0], a0, false);
        a1 = __builtin_amdgcn_fdot2(hv, w.h[1], a1, false);
        a2 = __builtin_amdgcn_fdot2(hv, w.h[2], a2, false);
        a3 = __builtin_amdgcn_fdot2(hv, w.h[3], a3, false);
      }
    }
    *reinterpret_cast<float4*>(&part[jg][grow]) = make_float4(a0,a1,a2,a3);
    __syncthreads();
    if (tid < 256){
      const float* xrow = xs + ((long)b*S + t)*2048 + dir*1024;
      float g0 = xrow[tid]
               + (part[0][tid]      + part[1][tid])      + (part[2][tid]      + part[3][tid]);
      float g1 = xrow[256+tid]
               + (part[0][256+tid]  + part[1][256+tid])  + (part[2][256+tid]  + part[3][256+tid]);
      float g2 = xrow[512+tid]
               + (part[0][512+tid]  + part[1][512+tid])  + (part[2][512+tid]  + part[3][512+tid]);
      float g3 = xrow[768+tid]
               + (part[0][768+tid]  + part[1][768+tid])  + (part[2][768+tid]  + part[3][768+tid]);
      cc = sigf(g1)*cc + sigf(g0)*tanh_f(g2);
      const float h = sigf(g3)*tanh_f(cc);
      hsh[tid] = (_Float16)h;
      const long o = ((long)b*S + t)*512 + dir*256 + tid;
      if (outf) outf[o] = h;
      if (outh) outh[o] = (_Float16)h;
    }
    __syncthreads();
  }
}

// ---------------------------------------------------------------------------
// K11: final LayerNorm(512) + classifier (5) per row
// ---------------------------------------------------------------------------
__global__ __launch_bounds__(128) void k_lncls(
  const float* __restrict__ in, const float* __restrict__ g,
  const float* __restrict__ b, const float* __restrict__ cw,
  const float* __restrict__ cb, float* __restrict__ out)
{
  const int row = blockIdx.x, tid = threadIdx.x;
  __shared__ float sred[4];
  __shared__ float cred[2][5];
  float4 v = *reinterpret_cast<const float4*>(in + (long)row*512 + tid*4);
  float s  = v.x+v.y+v.z+v.w;
  float sq = v.x*v.x+v.y*v.y+v.z*v.z+v.w*v.w;
  #pragma unroll
  for (int off=32; off>=1; off>>=1){ s += __shfl_xor(s, off); sq += __shfl_xor(sq, off); }
  const int wv = tid>>6;
  if ((tid&63)==0){ sred[wv*2]=s; sred[wv*2+1]=sq; }
  __syncthreads();
  const float S = sred[0]+sred[2], SQ = sred[1]+sred[3];
  const float m = S*(1.f/512.f);
  const float rstd = rsqrtf(SQ*(1.f/512.f) - m*m + 1e-5f);
  float4 gg = *reinterpret_cast<const float4*>(g + tid*4);
  float4 bb = *reinterpret_cast<const float4*>(b + tid*4);
  const float n0 = (v.x-m)*rstd*gg.x + bb.x;
  const float n1 = (v.y-m)*rstd*gg.y + bb.y;
  const float n2 = (v.z-m)*rstd*gg.z + bb.z;
  const float n3 = (v.w-m)*rstd*gg.w + bb.w;
  #pragma unroll
  for (int nc=0; nc<5; ++nc){
    float4 w = *reinterpret_cast<const float4*>(cw + nc*512 + tid*4);
    float p = n0*w.x + n1*w.y + n2*w.z + n3*w.w;
    #pragma unroll
    for (int off=32; off>=1; off>>=1) p += __shfl_xor(p, off);
    if ((tid&63)==0) cred[wv][nc] = p;
  }
  __syncthreads();
  if (tid < 5) out[(long)row*5 + tid] = cred[0][tid] + cred[1][tid] + cb[tid];
}

// ---------------------------------------------------------------------------
extern "C" void kernel_launch(void* const* d_in, const int* in_sizes, int n_in,
                              void* d_out, int out_size, void* d_ws, size_t ws_size,
                              hipStream_t stream)
{
  const float* x     = (const float*)d_in[0];
  const int*   ei    = (const int*)d_in[1];
  const float* w1    = (const float*)d_in[2];
  const float* c1b   = (const float*)d_in[3];
  const float* bg1   = (const float*)d_in[4];
  const float* bb1   = (const float*)d_in[5];
  const float* w2    = (const float*)d_in[6];
  const float* c2b   = (const float*)d_in[7];
  const float* bg2   = (const float*)d_in[8];
  const float* bb2   = (const float*)d_in[9];
  const float* w3    = (const float*)d_in[10];
  const float* c3b   = (const float*)d_in[11];
  const float* bg3   = (const float*)d_in[12];
  const float* bb3   = (const float*)d_in[13];
  const float* gcn0w = (const float*)d_in[14];
  const float* gcn0b = (const float*)d_in[15];
  const float* gcn1w = (const float*)d_in[16];
  const float* gcn1b = (const float*)d_in[17];
  const float* lng   = (const float*)d_in[18];
  const float* lnb   = (const float*)d_in[19];
  const float* wih0  = (const float*)d_in[20];
  const float* whh0  = (const float*)d_in[21];
  const float* bih0  = (const float*)d_in[22];
  const float* bhh0  = (const float*)d_in[23];
  const float* wih0r = (const float*)d_in[24];
  const float* whh0r = (const float*)d_in[25];
  const float* bih0r = (const float*)d_in[26];
  const float* bhh0r = (const float*)d_in[27];
  const float* wih1  = (const float*)d_in[28];
  const float* whh1  = (const float*)d_in[29];
  const float* bih1  = (const float*)d_in[30];
  const float* bhh1  = (const float*)d_in[31];
  const float* wih1r = (const float*)d_in[32];
  const float* whh1r = (const float*)d_in[33];
  const float* bih1r = (const float*)d_in[34];
  const float* bhh1r = (const float*)d_in[35];
  const float* lstmg = (const float*)d_in[36];
  const float* lstmb = (const float*)d_in[37];
  const float* clsw  = (const float*)d_in[38];
  const float* clsb  = (const float*)d_in[39];
  float* ws  = (float*)d_ws;
  float* out = (float*)d_out;

  // workspace layout (float offsets)
  float*    An      = ws + 0;                         // 64
  _Float16* bw2f    = (_Float16*)(ws + 64);           // 3072 h
  _Float16* bw3f    = (_Float16*)(ws + 1600);         // 6144 h
  _Float16* feats16 = (_Float16*)(ws + 4672);         // 655360 h
  _Float16* g1b16   = (_Float16*)(ws + 332352);       // 1310720 h
  _Float16* emb16   = (_Float16*)(ws + 987712);       // 163840 h
  _Float16* l0h     = (_Float16*)(ws + 1069632);      // 655360 h
  _Float16* w0f     = (_Float16*)(ws + 1397312);      // 131072 h
  _Float16* w0rf    = (_Float16*)(ws + 1462848);      // 131072 h
  _Float16* w1f     = (_Float16*)(ws + 1528384);      // 524288 h
  _Float16* w1rf    = (_Float16*)(ws + 1790528);      // 524288 h
  _Float16* gw0f    = (_Float16*)(ws + 2052672);      // 8192 h
  _Float16* gw1f    = (_Float16*)(ws + 2056768);      // 16384 h
  h2f16*    wt0f    = (h2f16*)(ws + 2064960);         // 131072 f each
  h2f16*    wt0r    = (h2f16*)(ws + 2196032);
  h2f16*    wt1f    = (h2f16*)(ws + 2327104);
  h2f16*    wt1r    = (h2f16*)(ws + 2458176);
  float*    l1f     = ws + 2589248;                   // 655360 f
  float*    xs      = ws + 3244608;                   // 2621440 f

  // Stage 0: fused prep
  k_prep<<<7289, 256, 0, stream>>>(ei, An, w2, w3, bg2, bg3, bw2f, bw3f,
                                   wih0, wih0r, wih1, wih1r, gcn0w, gcn1w,
                                   w0f, w0rf, w1f, w1rf, gw0f, gw1f,
                                   whh0, whh0r, whh1, whh1r,
                                   wt0f, wt0r, wt1f, wt1r);
  // Stage 1: conv front-end
  k_conv<<<10240, 512, 0, stream>>>(x, w1,c1b,bg1,bb1, bw2f,c2b,bg2,bb2,
                                    bw3f,c3b,bg3,bb3, feats16);

  // Stage 2: GCN (fused GEMM+mix)
  k_gcn1<<<dim3(2, 160), 256, 0, stream>>>(feats16, gw0f, An, gcn0b, g1b16, 64);
  k_gcn2<<<160, 256, 0, stream>>>(g1b16, gw1f, An, gcn1b, lng, lnb, emb16);

  // Stage 3: BiLSTM layer 0
  k_gemm_mf2<<<dim3(16, 20, 2), 256, 0, stream>>>(emb16, w0f, w0rf,
      bih0, bhh0, bih0r, bhh0r, xs, 1024, 1280, 1024, 128, 2048);
  k_lstm<<<128, 1024, 0, stream>>>(xs, wt0f, wt0r, nullptr, l0h);

  // BiLSTM layer 1
  k_gemm_mf2<<<dim3(16, 20, 2), 256, 0, stream>>>(l0h, w1f, w1rf,
      bih1, bhh1, bih1r, bhh1r, xs, 1024, 1280, 1024, 512, 2048);
  k_lstm<<<128, 1024, 0, stream>>>(xs, wt1f, wt1r, l1f, nullptr);

  // Stage 4: LN + classifier
  k_lncls<<<1280, 128, 0, stream>>>(l1f, lstmg, lstmb, clsw, clsb, out);
}